// Round 10
// baseline (183.123 us; speedup 1.0000x reference)
//
#include <hip/hip_runtime.h>
#include <hip/hip_bf16.h>
#include <cstdint>

#define B_ 4
#define H_ 80
#define W_ 80
#define CH_ 256
#define NC_ 22
#define DIM_ 256
#define NPIX (B_*H_*W_)

typedef unsigned short ushort;
typedef __attribute__((ext_vector_type(8))) short short8;     // 8 bf16 = 4 VGPR
typedef __attribute__((ext_vector_type(4))) float floatx4;    // MFMA C/D frag

__device__ __attribute__((aligned(256))) static const unsigned char zglob[256] = {};

static __device__ inline ushort f2bf(float v) {
    __hip_bfloat16 h = __float2bfloat16(v);   // RNE
    ushort r;
    __builtin_memcpy(&r, &h, 2);
    return r;
}
static __device__ inline unsigned pk2(float a, float b) {
    return (unsigned)f2bf(a) | ((unsigned)f2bf(b) << 16);
}
static __device__ inline void gll16(const void* g, void* l) {
    __builtin_amdgcn_global_load_lds((const __attribute__((address_space(1))) void*)g,
                                     (__attribute__((address_space(3))) void*)l, 16, 0, 0);
}

// ---------------------------------------------------------------------------
// prep: ONE launch fusing three independent jobs (r6/r7-proven, byte-identical)
// ---------------------------------------------------------------------------
__global__ __launch_bounds__(256) void prep(const float* __restrict__ seg,
                                            const float* __restrict__ cw,
                                            const float* __restrict__ x,
                                            float* __restrict__ ssel,
                                            ushort* __restrict__ wbT,
                                            ushort* __restrict__ xb)
{
    __shared__ ushort ls[32][260];
    if (blockIdx.x < 900) {
        const int t = blockIdx.x * 256 + threadIdx.x;     // = k*NPIX + m
        const int k = t / NPIX;
        const int m = t - k * NPIX;
        const int w = m % W_;
        const int h = (m / W_) % H_;
        const int b = m / (W_ * H_);

        const float2* c2 = (const float2*)(seg + (size_t)m * NC_);
        float cv[NC_];
        #pragma unroll
        for (int c = 0; c < NC_ / 2; ++c) { float2 v = c2[c]; cv[2*c] = v.x; cv[2*c+1] = v.y; }
        float mx = -1e30f;
        #pragma unroll
        for (int c = 0; c < NC_; ++c) mx = fmaxf(mx, cv[c]);

        const int i = k / 3, j = k % 3;
        const int hh = h + i - 1, ww = w + j - 1;
        float s = 0.f;
        if (hh >= 0 && hh < H_ && ww >= 0 && ww < W_) {
            const float2* n2 = (const float2*)(seg + ((size_t)((b * H_ + hh) * W_ + ww)) * NC_);
            #pragma unroll
            for (int c = 0; c < NC_ / 2; ++c) {
                float2 v = n2[c];
                s += (cv[2*c]   == mx) ? v.x : 0.f;
                s += (cv[2*c+1] == mx) ? v.y : 0.f;
            }
        }
        ssel[t] = s;                                      // RAW sel (norm in conv2)
    } else if (blockIdx.x < 972) {
        const int bx = blockIdx.x - 900;
        const int k  = bx / 8;
        const int c0 = (bx % 8) * 32;
        const int c    = threadIdx.x >> 3;                // 0..31
        const int seg8 = threadIdx.x & 7;                 // 0..7

        const float* src = cw + ((size_t)(c0 + c) * 9 + k) * DIM_ + seg8 * 32;
        #pragma unroll
        for (int e = 0; e < 32; e += 4) {
            float4 v = *(const float4*)(src + e);
            unsigned* dst = (unsigned*)&ls[c][seg8 * 32 + e];
            dst[0] = pk2(v.x, v.y);
            dst[1] = pk2(v.z, v.w);
        }
        __syncthreads();

        const int d = threadIdx.x;                        // 0..255
        ushort tmp[32];
        #pragma unroll
        for (int cc = 0; cc < 32; ++cc) tmp[cc] = ls[cc][d];
        uint4 o[4];
        __builtin_memcpy(o, tmp, 64);
        uint4* dst = (uint4*)(wbT + ((size_t)k * 256 + d) * 256 + c0);
        dst[0] = o[0]; dst[1] = o[1]; dst[2] = o[2]; dst[3] = o[3];
    } else if (xb != nullptr) {
        size_t idx = ((size_t)(blockIdx.x - 972) * 256 + threadIdx.x) * 8;
        const float4* s = (const float4*)(x + idx);
        float4 a = s[0], b = s[1];
        uint4 o = make_uint4(pk2(a.x, a.y), pk2(a.z, a.w), pk2(b.x, b.y), pk2(b.z, b.w));
        *(uint4*)(xb + idx) = o;
    }
}

// ---------------------------------------------------------------------------
// conv2: r7's PROVEN kernel (73.5 us) with GROUPED staging. 6 groups
// g = (i, cc-half); each group stages its 84-px haloed row-half ONCE
// (r8-verified addressing: LDS pixel p = col+1, chunk swz c^(p&7), gll
// direct with pre-swizzled source) and runs the 3 j-taps off it at read
// offset p = m + j.  Per-interval body is r7-verbatim (P[5][2], Breg[8],
// 4 kk, O += sl[k][m]*P).  Barriers 18 -> 6, stage traffic 3x less.
// B discipline: loadB(j+1) issued BEFORE stage (clean vmcnt); only the
// j=2 B-load sits behind the glls, with a full interval of slack.
// NO unroll pragma on the g-loop (r8's spill came from body inflation).
// ---------------------------------------------------------------------------
__global__ __launch_bounds__(256, 3) void conv2(const ushort* __restrict__ xb,
                                                const float* __restrict__ ssel,
                                                const ushort* __restrict__ wbT,
                                                float* __restrict__ out)
{
    __shared__ __attribute__((aligned(1024))) ushort xs[2][84 * 128];  // 43008 B
    __shared__ float sl[9][80];                                        // 2880 B

    const int tid  = threadIdx.x;
    const int lane = tid & 63;
    const int wv   = tid >> 6;               // d-offset wv*32
    const int ln   = lane & 15;
    const int quad = lane >> 4;
    const int rt   = blockIdx.x;             // b*H + h
    const int b    = rt / H_;
    const int h    = rt % H_;
    const int d0   = blockIdx.y * 128;

    floatx4 O[5][2];
    #pragma unroll
    for (int i = 0; i < 5; ++i)
        #pragma unroll
        for (int jn = 0; jn < 2; ++jn)
            O[i][jn] = (floatx4){0.f, 0.f, 0.f, 0.f};

    short8 Breg[8];                  // [kk][jn] for current tap (32 VGPR)
    auto loadB = [&](int k, int cc) {
        #pragma unroll
        for (int kk = 0; kk < 4; ++kk)
            #pragma unroll
            for (int jn = 0; jn < 2; ++jn)
                Breg[kk * 2 + jn] = *(const short8*)(wbT
                    + ((size_t)k * 256 + d0 + wv * 32 + jn * 16 + ln) * 256
                    + cc + kk * 32 + quad * 8);
    };

    // stage group g's (i, cc) row-half into xs[g&1]. 21 wave-chunks of 64x16B.
    // slot s: p = s>>4 (LDS pixel, col = p-1), cph = s&15 stores clog = cph^(p&7).
    // (r8-verified correct.)
    auto stage = [&](int g) {
        const int gi = g >> 1;
        const int cc = (g & 1) * 128;
        const int rr = h + gi - 1;
        const bool rowok = (rr >= 0) && (rr < H_);
        const ushort* xrow = xb + ((size_t)((b * H_ + (rowok ? rr : 0)) * W_)) * CH_ + cc;
        char* dbase = (char*)&xs[g & 1][0];
        #pragma unroll
        for (int r = 0; r < 5; ++r) {
            const int e    = r * 4 + wv;      // 0..19
            const int s    = e * 64 + lane;
            const int p    = s >> 4;          // 0..79
            const int cph  = s & 15;
            const int clog = cph ^ (p & 7);
            const bool v   = rowok && (p >= 1) && (p <= 80);
            const void* src = v ? (const void*)(xrow + (size_t)(p - 1) * CH_ + clog * 8)
                                : (const void*)zglob;
            gll16(src, dbase + (size_t)e * 1024);
        }
        if (wv == 0) {                        // wave-uniform tail chunk e=20
            const int s    = 20 * 64 + lane;
            const int p    = s >> 4;          // 80..83
            const int cph  = s & 15;
            const int clog = cph ^ (p & 7);
            const bool v   = rowok && (p <= 80);
            const void* src = v ? (const void*)(xrow + (size_t)(p - 1) * CH_ + clog * 8)
                                : (const void*)zglob;
            gll16(src, dbase + (size_t)20 * 1024);
        }
    };

    // ================= prologue =================
    stage(0);
    loadB(0, 0);
    if (tid < 80) {                           // fold norm into raw sel
        float rv[9]; int cnt = 0;
        #pragma unroll
        for (int k = 0; k < 9; ++k) {
            rv[k] = ssel[k * NPIX + rt * W_ + tid];
            cnt += (rv[k] != 0.f) ? 1 : 0;
        }
        const float norm = (cnt > 0) ? 9.f / (float)cnt : 0.f;
        #pragma unroll
        for (int k = 0; k < 9; ++k) sl[k][tid] = rv[k] * norm;
    }
    __syncthreads();                          // buf0 + Breg + sl ready

    // ================= main loop: 6 groups x 3 taps, one barrier/group ======
    for (int g = 0; g < 6; ++g) {
        const int gi = g >> 1;
        const int cc = (g & 1) * 128;
        const char* bp = (const char*)&xs[g & 1][0];

        #pragma unroll
        for (int j = 0; j < 3; ++j) {
            const int k = 3 * gi + j;

            floatx4 P[5][2];
            #pragma unroll
            for (int im = 0; im < 5; ++im)
                #pragma unroll
                for (int jn = 0; jn < 2; ++jn)
                    P[im][jn] = (floatx4){0.f, 0.f, 0.f, 0.f};

            #pragma unroll
            for (int kk = 0; kk < 4; ++kk) {
                short8 a[5];
                #pragma unroll
                for (int im = 0; im < 5; ++im) {
                    const int p = im * 16 + ln + j;          // LDS pixel row
                    a[im] = *(const short8*)(bp
                        + (size_t)p * 256
                        + ((((kk << 2) | quad) ^ (p & 7)) << 4));
                }
                #pragma unroll
                for (int im = 0; im < 5; ++im)
                    #pragma unroll
                    for (int jn = 0; jn < 2; ++jn)
                        P[im][jn] = __builtin_amdgcn_mfma_f32_16x16x32_bf16(
                            a[im], Breg[kk * 2 + jn], P[im][jn], 0, 0, 0);
            }

            // B prefetch (after last Breg use of this interval)
            if (j == 0) {
                loadB(k + 1, cc);             // clean: issued BEFORE the glls
                if (g < 5) stage(g + 1);      // glls drain at end-of-group barrier
            } else if (j == 1) {
                loadB(k + 1, cc);             // behind glls; 1 interval of slack
            } else if (g < 5) {
                loadB(3 * ((g + 1) >> 1), ((g + 1) & 1) * 128);  // used after bar
            }

            // O += sl[k][m] * P  (row m = im*16 + quad*4 + r)
            #pragma unroll
            for (int im = 0; im < 5; ++im) {
                const float4 sv = *(const float4*)&sl[k][im * 16 + quad * 4];
                #pragma unroll
                for (int jn = 0; jn < 2; ++jn) {
                    O[im][jn][0] += sv.x * P[im][jn][0];
                    O[im][jn][1] += sv.y * P[im][jn][1];
                    O[im][jn][2] += sv.z * P[im][jn][2];
                    O[im][jn][3] += sv.w * P[im][jn][3];
                }
            }
        }
        __syncthreads();                      // group done: stage(g+1) landed
    }

    // epilogue: C/D layout col(d)=lane&15, row(m)=quad*4+reg
    #pragma unroll
    for (int im = 0; im < 5; ++im) {
        #pragma unroll
        for (int jn = 0; jn < 2; ++jn) {
            const int dd = d0 + wv * 32 + jn * 16 + ln;
            #pragma unroll
            for (int r = 0; r < 4; ++r) {
                const int m = im * 16 + quad * 4 + r;
                out[((size_t)(rt * W_ + m)) * DIM_ + dd] = O[im][jn][r];
            }
        }
    }
}

// ---------------------------------------------------------------------------
// conv2_fb: r6-proven fp32 reg-staging fallback (workspace too small for xb).
// ---------------------------------------------------------------------------
__global__ __launch_bounds__(256, 3) void conv2_fb(const float* __restrict__ x,
                                                   const float* __restrict__ ssel,
                                                   const ushort* __restrict__ wbT,
                                                   float* __restrict__ out)
{
    __shared__ ushort xsA[2][80 * 136];
    __shared__ float  sl[9][80];

    const int tid  = threadIdx.x;
    const int lane = tid & 63;
    const int wv   = tid >> 6;
    const int ln   = lane & 15;
    const int quad = lane >> 4;
    const int rt   = blockIdx.x;
    const int b    = rt / H_;
    const int h    = rt % H_;
    const int d0   = blockIdx.y * 128;

    int qm[5], qc[5];
    #pragma unroll
    for (int r = 0; r < 5; ++r) { int q = tid + 256 * r; qm[r] = q >> 4; qc[r] = q & 15; }

    floatx4 O[5][2];
    #pragma unroll
    for (int i = 0; i < 5; ++i)
        #pragma unroll
        for (int jn = 0; jn < 2; ++jn)
            O[i][jn] = (floatx4){0.f, 0.f, 0.f, 0.f};

    float4 fa[5], fb[5];
    bool   ok[5];

    auto stage_load = [&](int nit) {
        const int i = nit / 6, rem = nit % 6, cc = (rem / 3) * 128, jj = rem % 3;
        const int rr = h + i - 1;
        const bool rowok = (rr >= 0) && (rr < H_);
        const int rsafe = rowok ? rr : h;
        #pragma unroll
        for (int r = 0; r < 5; ++r) {
            const int col = qm[r] + jj - 1;
            const bool v = rowok && (col >= 0) && (col < W_);
            ok[r] = v;
            const float* f = x + ((size_t)(b * H_ + rsafe) * W_ + (v ? col : 0)) * CH_ + cc + qc[r] * 8;
            fa[r] = *(const float4*)f;
            fb[r] = *(const float4*)(f + 4);
        }
    };
    auto stage_write = [&](int nit) {
        #pragma unroll
        for (int r = 0; r < 5; ++r) {
            uint4 v = ok[r] ? make_uint4(pk2(fa[r].x, fa[r].y), pk2(fa[r].z, fa[r].w),
                                         pk2(fb[r].x, fb[r].y), pk2(fb[r].z, fb[r].w))
                            : make_uint4(0u, 0u, 0u, 0u);
            *(uint4*)&xsA[nit & 1][qm[r] * 136 + qc[r] * 8] = v;
        }
    };

    short8 Breg[8];
    auto loadB = [&](int nit) {
        const int i = nit / 6, rem = nit % 6, cc = (rem / 3) * 128, jj = rem % 3;
        const int k = 3 * i + jj;
        #pragma unroll
        for (int kk = 0; kk < 4; ++kk)
            #pragma unroll
            for (int jn = 0; jn < 2; ++jn)
                Breg[kk * 2 + jn] = *(const short8*)(wbT
                    + ((size_t)k * 256 + d0 + wv * 32 + jn * 16 + ln) * 256
                    + cc + kk * 32 + quad * 8);
    };

    stage_load(0);
    if (tid < 80) {
        float rv[9]; int cnt = 0;
        #pragma unroll
        for (int k = 0; k < 9; ++k) { rv[k] = ssel[k * NPIX + rt * W_ + tid]; cnt += (rv[k] != 0.f) ? 1 : 0; }
        const float norm = (cnt > 0) ? 9.f / (float)cnt : 0.f;
        #pragma unroll
        for (int k = 0; k < 9; ++k) sl[k][tid] = rv[k] * norm;
    }
    stage_write(0);
    loadB(0);
    __syncthreads();

    #pragma unroll 2
    for (int it = 0; it < 18; ++it) {
        const int i = it / 6, rem = it % 6, jj = rem % 3;
        const int k = 3 * i + jj;
        const ushort* bp = xsA[it & 1];

        if (it < 17) stage_load(it + 1);

        floatx4 P[5][2];
        #pragma unroll
        for (int im = 0; im < 5; ++im)
            #pragma unroll
            for (int jn = 0; jn < 2; ++jn)
                P[im][jn] = (floatx4){0.f, 0.f, 0.f, 0.f};

        #pragma unroll
        for (int kk = 0; kk < 4; ++kk) {
            short8 a[5];
            #pragma unroll
            for (int im = 0; im < 5; ++im)
                a[im] = *(const short8*)&bp[(im * 16 + ln) * 136 + kk * 32 + quad * 8];
            #pragma unroll
            for (int im = 0; im < 5; ++im)
                #pragma unroll
                for (int jn = 0; jn < 2; ++jn)
                    P[im][jn] = __builtin_amdgcn_mfma_f32_16x16x32_bf16(
                        a[im], Breg[kk * 2 + jn], P[im][jn], 0, 0, 0);
        }

        if (it < 17) stage_write(it + 1);
        if (it < 17) loadB(it + 1);

        #pragma unroll
        for (int im = 0; im < 5; ++im) {
            const float4 sv = *(const float4*)&sl[k][im * 16 + quad * 4];
            #pragma unroll
            for (int jn = 0; jn < 2; ++jn) {
                O[im][jn][0] += sv.x * P[im][jn][0];
                O[im][jn][1] += sv.y * P[im][jn][1];
                O[im][jn][2] += sv.z * P[im][jn][2];
                O[im][jn][3] += sv.w * P[im][jn][3];
            }
        }
        __syncthreads();
    }

    #pragma unroll
    for (int im = 0; im < 5; ++im)
        #pragma unroll
        for (int jn = 0; jn < 2; ++jn) {
            const int dd = d0 + wv * 32 + jn * 16 + ln;
            #pragma unroll
            for (int r = 0; r < 4; ++r) {
                const int m = im * 16 + quad * 4 + r;
                out[((size_t)(rt * W_ + m)) * DIM_ + dd] = O[im][jn][r];
            }
        }
}

extern "C" void kernel_launch(void* const* d_in, const int* in_sizes, int n_in,
                              void* d_out, int out_size, void* d_ws, size_t ws_size,
                              hipStream_t stream)
{
    const float* x   = (const float*)d_in[0];   // (4,80,80,256) f32
    const float* seg = (const float*)d_in[1];   // (4,80,80,22)  f32
    const float* cw  = (const float*)d_in[2];   // (256,3,3,256) f32
    float* out = (float*)d_out;

    float*  ssel = (float*)d_ws;                                   // 921600 B (raw)
    ushort* wbT  = (ushort*)((char*)d_ws + 921600);                // 1179648 B
    ushort* xb   = (ushort*)((char*)d_ws + 921600 + 1179648);      // 13107200 B
    const size_t need = 921600u + 1179648u + 13107200u;

    if (ws_size >= need) {
        prep<<<dim3(972 + 3200), dim3(256), 0, stream>>>(seg, cw, x, ssel, wbT, xb);
        conv2<<<dim3(B_ * H_, 2), dim3(256), 0, stream>>>(xb, ssel, wbT, out);
    } else {
        prep<<<dim3(972), dim3(256), 0, stream>>>(seg, cw, x, ssel, wbT, nullptr);
        conv2_fb<<<dim3(B_ * H_, 2), dim3(256), 0, stream>>>(x, ssel, wbT, out);
    }
}

// Round 11
// 146.740 us; speedup vs baseline: 1.2479x; 1.2479x over previous
//
#include <hip/hip_runtime.h>
#include <hip/hip_bf16.h>
#include <cstdint>

#define B_ 4
#define H_ 80
#define W_ 80
#define CH_ 256
#define NC_ 22
#define DIM_ 256
#define NPIX (B_*H_*W_)

typedef unsigned short ushort;
typedef __attribute__((ext_vector_type(8))) short short8;     // 8 bf16 = 4 VGPR
typedef __attribute__((ext_vector_type(4))) float floatx4;    // MFMA C/D frag

__device__ __attribute__((aligned(256))) static const unsigned char zglob[256] = {};

static __device__ inline ushort f2bf(float v) {
    __hip_bfloat16 h = __float2bfloat16(v);   // RNE
    ushort r;
    __builtin_memcpy(&r, &h, 2);
    return r;
}
static __device__ inline unsigned pk2(float a, float b) {
    return (unsigned)f2bf(a) | ((unsigned)f2bf(b) << 16);
}
static __device__ inline void gll16(const void* g, void* l) {
    __builtin_amdgcn_global_load_lds((const __attribute__((address_space(1))) void*)g,
                                     (__attribute__((address_space(3))) void*)l, 16, 0, 0);
}

// ---------------------------------------------------------------------------
// prep: ONE launch fusing three independent jobs (r6/r7-proven, byte-identical)
// ---------------------------------------------------------------------------
__global__ __launch_bounds__(256) void prep(const float* __restrict__ seg,
                                            const float* __restrict__ cw,
                                            const float* __restrict__ x,
                                            float* __restrict__ ssel,
                                            ushort* __restrict__ wbT,
                                            ushort* __restrict__ xb)
{
    __shared__ ushort ls[32][260];
    if (blockIdx.x < 900) {
        const int t = blockIdx.x * 256 + threadIdx.x;     // = k*NPIX + m
        const int k = t / NPIX;
        const int m = t - k * NPIX;
        const int w = m % W_;
        const int h = (m / W_) % H_;
        const int b = m / (W_ * H_);

        const float2* c2 = (const float2*)(seg + (size_t)m * NC_);
        float cv[NC_];
        #pragma unroll
        for (int c = 0; c < NC_ / 2; ++c) { float2 v = c2[c]; cv[2*c] = v.x; cv[2*c+1] = v.y; }
        float mx = -1e30f;
        #pragma unroll
        for (int c = 0; c < NC_; ++c) mx = fmaxf(mx, cv[c]);

        const int i = k / 3, j = k % 3;
        const int hh = h + i - 1, ww = w + j - 1;
        float s = 0.f;
        if (hh >= 0 && hh < H_ && ww >= 0 && ww < W_) {
            const float2* n2 = (const float2*)(seg + ((size_t)((b * H_ + hh) * W_ + ww)) * NC_);
            #pragma unroll
            for (int c = 0; c < NC_ / 2; ++c) {
                float2 v = n2[c];
                s += (cv[2*c]   == mx) ? v.x : 0.f;
                s += (cv[2*c+1] == mx) ? v.y : 0.f;
            }
        }
        ssel[t] = s;                                      // RAW sel (norm in conv2)
    } else if (blockIdx.x < 972) {
        const int bx = blockIdx.x - 900;
        const int k  = bx / 8;
        const int c0 = (bx % 8) * 32;
        const int c    = threadIdx.x >> 3;                // 0..31
        const int seg8 = threadIdx.x & 7;                 // 0..7

        const float* src = cw + ((size_t)(c0 + c) * 9 + k) * DIM_ + seg8 * 32;
        #pragma unroll
        for (int e = 0; e < 32; e += 4) {
            float4 v = *(const float4*)(src + e);
            unsigned* dst = (unsigned*)&ls[c][seg8 * 32 + e];
            dst[0] = pk2(v.x, v.y);
            dst[1] = pk2(v.z, v.w);
        }
        __syncthreads();

        const int d = threadIdx.x;                        // 0..255
        ushort tmp[32];
        #pragma unroll
        for (int cc = 0; cc < 32; ++cc) tmp[cc] = ls[cc][d];
        uint4 o[4];
        __builtin_memcpy(o, tmp, 64);
        uint4* dst = (uint4*)(wbT + ((size_t)k * 256 + d) * 256 + c0);
        dst[0] = o[0]; dst[1] = o[1]; dst[2] = o[2]; dst[3] = o[3];
    } else if (xb != nullptr) {
        size_t idx = ((size_t)(blockIdx.x - 972) * 256 + threadIdx.x) * 8;
        const float4* s = (const float4*)(x + idx);
        float4 a = s[0], b = s[1];
        uint4 o = make_uint4(pk2(a.x, a.y), pk2(a.z, a.w), pk2(b.x, b.y), pk2(b.z, b.w));
        *(uint4*)(xb + idx) = o;
    }
}

// ---------------------------------------------------------------------------
// conv2: r7's PROVEN 18-interval loop (73.5 us) with GROUPED staging, body
// kept UN-CLONED (#pragma unroll 1) to avoid the r8/r10 spills.
// Groups g = it/3 = (i, cc-half); the 84-px haloed row-half is staged ONCE
// per group (r8/r10-verified addressing: LDS pixel p = col+1, chunk swz
// c^(p&7), gll direct, pre-swizzled source); the 3 j-taps read it at
// row p = m + jj. Heavy barrier (gll drain) only at jj==0 intervals; the
// other 12 barriers drain only Breg loads. loadB(it+1) decode is r7-verbatim
// (interval order it = 6i + 3cci + j matches). Runtime g/jj counters.
// ---------------------------------------------------------------------------
__global__ __launch_bounds__(256, 3) void conv2(const ushort* __restrict__ xb,
                                                const float* __restrict__ ssel,
                                                const ushort* __restrict__ wbT,
                                                float* __restrict__ out)
{
    __shared__ __attribute__((aligned(1024))) ushort xs[2][84 * 128];  // 43008 B
    __shared__ float sl[9][80];                                        // 2880 B

    const int tid  = threadIdx.x;
    const int lane = tid & 63;
    const int wv   = tid >> 6;               // d-offset wv*32
    const int ln   = lane & 15;
    const int quad = lane >> 4;
    const int rt   = blockIdx.x;             // b*H + h
    const int b    = rt / H_;
    const int h    = rt % H_;
    const int d0   = blockIdx.y * 128;

    floatx4 O[5][2];
    #pragma unroll
    for (int i = 0; i < 5; ++i)
        #pragma unroll
        for (int jn = 0; jn < 2; ++jn)
            O[i][jn] = (floatx4){0.f, 0.f, 0.f, 0.f};

    short8 Breg[8];                  // [kk][jn] for current interval (32 VGPR)
    auto loadB = [&](int nit) {      // r7-verbatim decode
        const int i   = nit / 6;
        const int rem = nit % 6;
        const int cc  = (rem / 3) * 128;
        const int jj  = rem % 3;
        const int k   = 3 * i + jj;
        #pragma unroll
        for (int kk = 0; kk < 4; ++kk)
            #pragma unroll
            for (int jn = 0; jn < 2; ++jn)
                Breg[kk * 2 + jn] = *(const short8*)(wbT
                    + ((size_t)k * 256 + d0 + wv * 32 + jn * 16 + ln) * 256
                    + cc + kk * 32 + quad * 8);
    };

    // stage group gg's (i, cc) 84-px haloed row-half into xs[gg&1].
    // 21 wave-chunks of 64x16B. slot s: p = s>>4 (LDS pixel, col = p-1),
    // cph = s&15 stores global chunk clog = cph^(p&7). (r8/r10-verified.)
    auto stage_group = [&](int gg) {
        const int gi = gg >> 1;
        const int cc = (gg & 1) * 128;
        const int rr = h + gi - 1;
        const bool rowok = (rr >= 0) && (rr < H_);
        const ushort* xrow = xb + ((size_t)((b * H_ + (rowok ? rr : 0)) * W_)) * CH_ + cc;
        char* dbase = (char*)&xs[gg & 1][0];
        #pragma unroll
        for (int r = 0; r < 5; ++r) {
            const int e    = r * 4 + wv;      // 0..19
            const int s    = e * 64 + lane;
            const int p    = s >> 4;          // 0..79
            const int cph  = s & 15;
            const int clog = cph ^ (p & 7);
            const bool v   = rowok && (p >= 1) && (p <= 80);
            const void* src = v ? (const void*)(xrow + (size_t)(p - 1) * CH_ + clog * 8)
                                : (const void*)zglob;
            gll16(src, dbase + (size_t)e * 1024);
        }
        if (wv == 0) {                        // wave-uniform tail chunk e=20
            const int s    = 20 * 64 + lane;
            const int p    = s >> 4;          // 80..83
            const int cph  = s & 15;
            const int clog = cph ^ (p & 7);
            const bool v   = rowok && (p <= 80);
            const void* src = v ? (const void*)(xrow + (size_t)(p - 1) * CH_ + clog * 8)
                                : (const void*)zglob;
            gll16(src, dbase + (size_t)20 * 1024);
        }
    };

    // ================= prologue =================
    stage_group(0);
    loadB(0);
    if (tid < 80) {                           // fold norm into raw sel
        float rv[9]; int cnt = 0;
        #pragma unroll
        for (int k = 0; k < 9; ++k) {
            rv[k] = ssel[k * NPIX + rt * W_ + tid];
            cnt += (rv[k] != 0.f) ? 1 : 0;
        }
        const float norm = (cnt > 0) ? 9.f / (float)cnt : 0.f;
        #pragma unroll
        for (int k = 0; k < 9; ++k) sl[k][tid] = rv[k] * norm;
    }
    __syncthreads();                          // buf0 + Breg + sl ready

    // ================= main loop: 18 intervals, body NOT cloned =============
    int g = 0, jj = 0;                        // group = it/3, tap-col = it%3
    #pragma unroll 1
    for (int it = 0; it < 18; ++it) {
        const int k = 3 * (g >> 1) + jj;      // tap index
        const char* bp = (const char*)&xs[g & 1][0];

        if (jj == 0 && g < 5) stage_group(g + 1);   // once per group; drains
                                                    // at THIS interval's barrier
        floatx4 P[5][2];
        #pragma unroll
        for (int im = 0; im < 5; ++im)
            #pragma unroll
            for (int jn = 0; jn < 2; ++jn)
                P[im][jn] = (floatx4){0.f, 0.f, 0.f, 0.f};

        #pragma unroll
        for (int kk = 0; kk < 4; ++kk) {
            short8 a[5];
            #pragma unroll
            for (int im = 0; im < 5; ++im) {
                const int p = im * 16 + ln + jj;     // LDS pixel row
                a[im] = *(const short8*)(bp
                    + (size_t)p * 256
                    + ((((kk << 2) | quad) ^ (p & 7)) << 4));
            }
            #pragma unroll
            for (int im = 0; im < 5; ++im)
                #pragma unroll
                for (int jn = 0; jn < 2; ++jn)
                    P[im][jn] = __builtin_amdgcn_mfma_f32_16x16x32_bf16(
                        a[im], Breg[kk * 2 + jn], P[im][jn], 0, 0, 0);
        }

        if (it < 17) loadB(it + 1);          // after last Breg use; used after bar

        // scale-accumulate: O += s_k[m] * P  (row m = im*16 + quad*4 + r)
        #pragma unroll
        for (int im = 0; im < 5; ++im) {
            const float4 sv = *(const float4*)&sl[k][im * 16 + quad * 4];
            #pragma unroll
            for (int jn = 0; jn < 2; ++jn) {
                O[im][jn][0] += sv.x * P[im][jn][0];
                O[im][jn][1] += sv.y * P[im][jn][1];
                O[im][jn][2] += sv.z * P[im][jn][2];
                O[im][jn][3] += sv.w * P[im][jn][3];
            }
        }
        __syncthreads();
        if (++jj == 3) { jj = 0; ++g; }
    }

    // epilogue: C/D layout col(d)=lane&15, row(m)=quad*4+reg
    #pragma unroll
    for (int im = 0; im < 5; ++im) {
        #pragma unroll
        for (int jn = 0; jn < 2; ++jn) {
            const int dd = d0 + wv * 32 + jn * 16 + ln;
            #pragma unroll
            for (int r = 0; r < 4; ++r) {
                const int m = im * 16 + quad * 4 + r;
                out[((size_t)(rt * W_ + m)) * DIM_ + dd] = O[im][jn][r];
            }
        }
    }
}

// ---------------------------------------------------------------------------
// conv2_fb: r6-proven fp32 reg-staging fallback (workspace too small for xb).
// ---------------------------------------------------------------------------
__global__ __launch_bounds__(256, 3) void conv2_fb(const float* __restrict__ x,
                                                   const float* __restrict__ ssel,
                                                   const ushort* __restrict__ wbT,
                                                   float* __restrict__ out)
{
    __shared__ ushort xsA[2][80 * 136];
    __shared__ float  sl[9][80];

    const int tid  = threadIdx.x;
    const int lane = tid & 63;
    const int wv   = tid >> 6;
    const int ln   = lane & 15;
    const int quad = lane >> 4;
    const int rt   = blockIdx.x;
    const int b    = rt / H_;
    const int h    = rt % H_;
    const int d0   = blockIdx.y * 128;

    int qm[5], qc[5];
    #pragma unroll
    for (int r = 0; r < 5; ++r) { int q = tid + 256 * r; qm[r] = q >> 4; qc[r] = q & 15; }

    floatx4 O[5][2];
    #pragma unroll
    for (int i = 0; i < 5; ++i)
        #pragma unroll
        for (int jn = 0; jn < 2; ++jn)
            O[i][jn] = (floatx4){0.f, 0.f, 0.f, 0.f};

    float4 fa[5], fb[5];
    bool   ok[5];

    auto stage_load = [&](int nit) {
        const int i = nit / 6, rem = nit % 6, cc = (rem / 3) * 128, jj = rem % 3;
        const int rr = h + i - 1;
        const bool rowok = (rr >= 0) && (rr < H_);
        const int rsafe = rowok ? rr : h;
        #pragma unroll
        for (int r = 0; r < 5; ++r) {
            const int col = qm[r] + jj - 1;
            const bool v = rowok && (col >= 0) && (col < W_);
            ok[r] = v;
            const float* f = x + ((size_t)(b * H_ + rsafe) * W_ + (v ? col : 0)) * CH_ + cc + qc[r] * 8;
            fa[r] = *(const float4*)f;
            fb[r] = *(const float4*)(f + 4);
        }
    };
    auto stage_write = [&](int nit) {
        #pragma unroll
        for (int r = 0; r < 5; ++r) {
            uint4 v = ok[r] ? make_uint4(pk2(fa[r].x, fa[r].y), pk2(fa[r].z, fa[r].w),
                                         pk2(fb[r].x, fb[r].y), pk2(fb[r].z, fb[r].w))
                            : make_uint4(0u, 0u, 0u, 0u);
            *(uint4*)&xsA[nit & 1][qm[r] * 136 + qc[r] * 8] = v;
        }
    };

    short8 Breg[8];
    auto loadB = [&](int nit) {
        const int i = nit / 6, rem = nit % 6, cc = (rem / 3) * 128, jj = rem % 3;
        const int k = 3 * i + jj;
        #pragma unroll
        for (int kk = 0; kk < 4; ++kk)
            #pragma unroll
            for (int jn = 0; jn < 2; ++jn)
                Breg[kk * 2 + jn] = *(const short8*)(wbT
                    + ((size_t)k * 256 + d0 + wv * 32 + jn * 16 + ln) * 256
                    + cc + kk * 32 + quad * 8);
    };

    stage_load(0);
    if (tid < 80) {
        float rv[9]; int cnt = 0;
        #pragma unroll
        for (int k = 0; k < 9; ++k) { rv[k] = ssel[k * NPIX + rt * W_ + tid]; cnt += (rv[k] != 0.f) ? 1 : 0; }
        const float norm = (cnt > 0) ? 9.f / (float)cnt : 0.f;
        #pragma unroll
        for (int k = 0; k < 9; ++k) sl[k][tid] = rv[k] * norm;
    }
    stage_write(0);
    loadB(0);
    __syncthreads();

    #pragma unroll 2
    for (int it = 0; it < 18; ++it) {
        const int i = it / 6, rem = it % 6, jj = rem % 3;
        const int k = 3 * i + jj;
        const ushort* bp = xsA[it & 1];

        if (it < 17) stage_load(it + 1);

        floatx4 P[5][2];
        #pragma unroll
        for (int im = 0; im < 5; ++im)
            #pragma unroll
            for (int jn = 0; jn < 2; ++jn)
                P[im][jn] = (floatx4){0.f, 0.f, 0.f, 0.f};

        #pragma unroll
        for (int kk = 0; kk < 4; ++kk) {
            short8 a[5];
            #pragma unroll
            for (int im = 0; im < 5; ++im)
                a[im] = *(const short8*)&bp[(im * 16 + ln) * 136 + kk * 32 + quad * 8];
            #pragma unroll
            for (int im = 0; im < 5; ++im)
                #pragma unroll
                for (int jn = 0; jn < 2; ++jn)
                    P[im][jn] = __builtin_amdgcn_mfma_f32_16x16x32_bf16(
                        a[im], Breg[kk * 2 + jn], P[im][jn], 0, 0, 0);
        }

        if (it < 17) stage_write(it + 1);
        if (it < 17) loadB(it + 1);

        #pragma unroll
        for (int im = 0; im < 5; ++im) {
            const float4 sv = *(const float4*)&sl[k][im * 16 + quad * 4];
            #pragma unroll
            for (int jn = 0; jn < 2; ++jn) {
                O[im][jn][0] += sv.x * P[im][jn][0];
                O[im][jn][1] += sv.y * P[im][jn][1];
                O[im][jn][2] += sv.z * P[im][jn][2];
                O[im][jn][3] += sv.w * P[im][jn][3];
            }
        }
        __syncthreads();
    }

    #pragma unroll
    for (int im = 0; im < 5; ++im)
        #pragma unroll
        for (int jn = 0; jn < 2; ++jn) {
            const int dd = d0 + wv * 32 + jn * 16 + ln;
            #pragma unroll
            for (int r = 0; r < 4; ++r) {
                const int m = im * 16 + quad * 4 + r;
                out[((size_t)(rt * W_ + m)) * DIM_ + dd] = O[im][jn][r];
            }
        }
}

extern "C" void kernel_launch(void* const* d_in, const int* in_sizes, int n_in,
                              void* d_out, int out_size, void* d_ws, size_t ws_size,
                              hipStream_t stream)
{
    const float* x   = (const float*)d_in[0];   // (4,80,80,256) f32
    const float* seg = (const float*)d_in[1];   // (4,80,80,22)  f32
    const float* cw  = (const float*)d_in[2];   // (256,3,3,256) f32
    float* out = (float*)d_out;

    float*  ssel = (float*)d_ws;                                   // 921600 B (raw)
    ushort* wbT  = (ushort*)((char*)d_ws + 921600);                // 1179648 B
    ushort* xb   = (ushort*)((char*)d_ws + 921600 + 1179648);      // 13107200 B
    const size_t need = 921600u + 1179648u + 13107200u;

    if (ws_size >= need) {
        prep<<<dim3(972 + 3200), dim3(256), 0, stream>>>(seg, cw, x, ssel, wbT, xb);
        conv2<<<dim3(B_ * H_, 2), dim3(256), 0, stream>>>(xb, ssel, wbT, out);
    } else {
        prep<<<dim3(972), dim3(256), 0, stream>>>(seg, cw, x, ssel, wbT, nullptr);
        conv2_fb<<<dim3(B_ * H_, 2), dim3(256), 0, stream>>>(x, ssel, wbT, out);
    }
}

// Round 12
// 144.253 us; speedup vs baseline: 1.2695x; 1.0172x over previous
//
#include <hip/hip_runtime.h>
#include <hip/hip_bf16.h>
#include <cstdint>

#define B_ 4
#define H_ 80
#define W_ 80
#define CH_ 256
#define NC_ 22
#define DIM_ 256
#define NPIX (B_*H_*W_)

typedef unsigned short ushort;
typedef __attribute__((ext_vector_type(8))) short short8;     // 8 bf16 = 4 VGPR
typedef __attribute__((ext_vector_type(4))) float floatx4;    // MFMA C/D frag

__device__ __attribute__((aligned(256))) static const unsigned char zglob[256] = {};

static __device__ inline ushort f2bf(float v) {
    __hip_bfloat16 h = __float2bfloat16(v);   // RNE
    ushort r;
    __builtin_memcpy(&r, &h, 2);
    return r;
}
static __device__ inline unsigned pk2(float a, float b) {
    return (unsigned)f2bf(a) | ((unsigned)f2bf(b) << 16);
}
static __device__ inline void gll16(const void* g, void* l) {
    __builtin_amdgcn_global_load_lds((const __attribute__((address_space(1))) void*)g,
                                     (__attribute__((address_space(3))) void*)l, 16, 0, 0);
}

// ---------------------------------------------------------------------------
// prep: ONE launch fusing three independent jobs (r6/r7-proven, byte-identical)
// ---------------------------------------------------------------------------
__global__ __launch_bounds__(256) void prep(const float* __restrict__ seg,
                                            const float* __restrict__ cw,
                                            const float* __restrict__ x,
                                            float* __restrict__ ssel,
                                            ushort* __restrict__ wbT,
                                            ushort* __restrict__ xb)
{
    __shared__ ushort ls[32][260];
    if (blockIdx.x < 900) {
        const int t = blockIdx.x * 256 + threadIdx.x;     // = k*NPIX + m
        const int k = t / NPIX;
        const int m = t - k * NPIX;
        const int w = m % W_;
        const int h = (m / W_) % H_;
        const int b = m / (W_ * H_);

        const float2* c2 = (const float2*)(seg + (size_t)m * NC_);
        float cv[NC_];
        #pragma unroll
        for (int c = 0; c < NC_ / 2; ++c) { float2 v = c2[c]; cv[2*c] = v.x; cv[2*c+1] = v.y; }
        float mx = -1e30f;
        #pragma unroll
        for (int c = 0; c < NC_; ++c) mx = fmaxf(mx, cv[c]);

        const int i = k / 3, j = k % 3;
        const int hh = h + i - 1, ww = w + j - 1;
        float s = 0.f;
        if (hh >= 0 && hh < H_ && ww >= 0 && ww < W_) {
            const float2* n2 = (const float2*)(seg + ((size_t)((b * H_ + hh) * W_ + ww)) * NC_);
            #pragma unroll
            for (int c = 0; c < NC_ / 2; ++c) {
                float2 v = n2[c];
                s += (cv[2*c]   == mx) ? v.x : 0.f;
                s += (cv[2*c+1] == mx) ? v.y : 0.f;
            }
        }
        ssel[t] = s;                                      // RAW sel (norm in conv2)
    } else if (blockIdx.x < 972) {
        const int bx = blockIdx.x - 900;
        const int k  = bx / 8;
        const int c0 = (bx % 8) * 32;
        const int c    = threadIdx.x >> 3;                // 0..31
        const int seg8 = threadIdx.x & 7;                 // 0..7

        const float* src = cw + ((size_t)(c0 + c) * 9 + k) * DIM_ + seg8 * 32;
        #pragma unroll
        for (int e = 0; e < 32; e += 4) {
            float4 v = *(const float4*)(src + e);
            unsigned* dst = (unsigned*)&ls[c][seg8 * 32 + e];
            dst[0] = pk2(v.x, v.y);
            dst[1] = pk2(v.z, v.w);
        }
        __syncthreads();

        const int d = threadIdx.x;                        // 0..255
        ushort tmp[32];
        #pragma unroll
        for (int cc = 0; cc < 32; ++cc) tmp[cc] = ls[cc][d];
        uint4 o[4];
        __builtin_memcpy(o, tmp, 64);
        uint4* dst = (uint4*)(wbT + ((size_t)k * 256 + d) * 256 + c0);
        dst[0] = o[0]; dst[1] = o[1]; dst[2] = o[2]; dst[3] = o[3];
    } else if (xb != nullptr) {
        size_t idx = ((size_t)(blockIdx.x - 972) * 256 + threadIdx.x) * 8;
        const float4* s = (const float4*)(x + idx);
        float4 a = s[0], b = s[1];
        uint4 o = make_uint4(pk2(a.x, a.y), pk2(a.z, a.w), pk2(b.x, b.y), pk2(b.z, b.w));
        *(uint4*)(xb + idx) = o;
    }
}

// ---------------------------------------------------------------------------
// conv2: r11 (70 us) with the 12 LIGHT barriers removed. Only the group-end
// barrier remains (6 total): within a group the 3 j-taps read the SAME
// immutable buffer (no hazard), and Breg is per-wave registers ordered by
// the compiler's own vmcnt. stage_group(g+1) is issued AFTER loadB(j1) so
// the j1 B-loads sit ahead of the 21 glls in the in-order VMEM queue; by
// j2 the glls are ~2 intervals old and retired. Body stays un-cloned
// (#pragma unroll 1) to avoid the r8/r10 spills. All addressing byte-
// identical to r11 (r8/r10/r11-verified).
// ---------------------------------------------------------------------------
__global__ __launch_bounds__(256, 3) void conv2(const ushort* __restrict__ xb,
                                                const float* __restrict__ ssel,
                                                const ushort* __restrict__ wbT,
                                                float* __restrict__ out)
{
    __shared__ __attribute__((aligned(1024))) ushort xs[2][84 * 128];  // 43008 B
    __shared__ float sl[9][80];                                        // 2880 B

    const int tid  = threadIdx.x;
    const int lane = tid & 63;
    const int wv   = tid >> 6;               // d-offset wv*32
    const int ln   = lane & 15;
    const int quad = lane >> 4;
    const int rt   = blockIdx.x;             // b*H + h
    const int b    = rt / H_;
    const int h    = rt % H_;
    const int d0   = blockIdx.y * 128;

    floatx4 O[5][2];
    #pragma unroll
    for (int i = 0; i < 5; ++i)
        #pragma unroll
        for (int jn = 0; jn < 2; ++jn)
            O[i][jn] = (floatx4){0.f, 0.f, 0.f, 0.f};

    short8 Breg[8];                  // [kk][jn] for current interval (32 VGPR)
    auto loadB = [&](int nit) {      // r7-verbatim decode
        const int i   = nit / 6;
        const int rem = nit % 6;
        const int cc  = (rem / 3) * 128;
        const int jj  = rem % 3;
        const int k   = 3 * i + jj;
        #pragma unroll
        for (int kk = 0; kk < 4; ++kk)
            #pragma unroll
            for (int jn = 0; jn < 2; ++jn)
                Breg[kk * 2 + jn] = *(const short8*)(wbT
                    + ((size_t)k * 256 + d0 + wv * 32 + jn * 16 + ln) * 256
                    + cc + kk * 32 + quad * 8);
    };

    // stage group gg's (i, cc) 84-px haloed row-half into xs[gg&1].
    // 21 wave-chunks of 64x16B. slot s: p = s>>4 (LDS pixel, col = p-1),
    // cph = s&15 stores global chunk clog = cph^(p&7). (r8/r10/r11-verified.)
    auto stage_group = [&](int gg) {
        const int gi = gg >> 1;
        const int cc = (gg & 1) * 128;
        const int rr = h + gi - 1;
        const bool rowok = (rr >= 0) && (rr < H_);
        const ushort* xrow = xb + ((size_t)((b * H_ + (rowok ? rr : 0)) * W_)) * CH_ + cc;
        char* dbase = (char*)&xs[gg & 1][0];
        #pragma unroll
        for (int r = 0; r < 5; ++r) {
            const int e    = r * 4 + wv;      // 0..19
            const int s    = e * 64 + lane;
            const int p    = s >> 4;          // 0..79
            const int cph  = s & 15;
            const int clog = cph ^ (p & 7);
            const bool v   = rowok && (p >= 1) && (p <= 80);
            const void* src = v ? (const void*)(xrow + (size_t)(p - 1) * CH_ + clog * 8)
                                : (const void*)zglob;
            gll16(src, dbase + (size_t)e * 1024);
        }
        if (wv == 0) {                        // wave-uniform tail chunk e=20
            const int s    = 20 * 64 + lane;
            const int p    = s >> 4;          // 80..83
            const int cph  = s & 15;
            const int clog = cph ^ (p & 7);
            const bool v   = rowok && (p <= 80);
            const void* src = v ? (const void*)(xrow + (size_t)(p - 1) * CH_ + clog * 8)
                                : (const void*)zglob;
            gll16(src, dbase + (size_t)20 * 1024);
        }
    };

    // ================= prologue =================
    stage_group(0);
    loadB(0);
    if (tid < 80) {                           // fold norm into raw sel
        float rv[9]; int cnt = 0;
        #pragma unroll
        for (int k = 0; k < 9; ++k) {
            rv[k] = ssel[k * NPIX + rt * W_ + tid];
            cnt += (rv[k] != 0.f) ? 1 : 0;
        }
        const float norm = (cnt > 0) ? 9.f / (float)cnt : 0.f;
        #pragma unroll
        for (int k = 0; k < 9; ++k) sl[k][tid] = rv[k] * norm;
    }
    __syncthreads();                          // buf0 + Breg + sl ready

    // ========== main loop: 18 intervals, ONE barrier per group (6) ==========
    int g = 0, jj = 0;                        // group = it/3, tap-col = it%3
    #pragma unroll 1
    for (int it = 0; it < 18; ++it) {
        const int k = 3 * (g >> 1) + jj;      // tap index
        const char* bp = (const char*)&xs[g & 1][0];

        floatx4 P[5][2];
        #pragma unroll
        for (int im = 0; im < 5; ++im)
            #pragma unroll
            for (int jn = 0; jn < 2; ++jn)
                P[im][jn] = (floatx4){0.f, 0.f, 0.f, 0.f};

        #pragma unroll
        for (int kk = 0; kk < 4; ++kk) {
            short8 a[5];
            #pragma unroll
            for (int im = 0; im < 5; ++im) {
                const int p = im * 16 + ln + jj;     // LDS pixel row
                a[im] = *(const short8*)(bp
                    + (size_t)p * 256
                    + ((((kk << 2) | quad) ^ (p & 7)) << 4));
            }
            #pragma unroll
            for (int im = 0; im < 5; ++im)
                #pragma unroll
                for (int jn = 0; jn < 2; ++jn)
                    P[im][jn] = __builtin_amdgcn_mfma_f32_16x16x32_bf16(
                        a[im], Breg[kk * 2 + jn], P[im][jn], 0, 0, 0);
        }

        if (it < 17) loadB(it + 1);          // B ahead of glls in the VMEM queue

        if (jj == 0 && g < 5) stage_group(g + 1);   // glls drain at group barrier

        // scale-accumulate: O += s_k[m] * P  (row m = im*16 + quad*4 + r)
        #pragma unroll
        for (int im = 0; im < 5; ++im) {
            const float4 sv = *(const float4*)&sl[k][im * 16 + quad * 4];
            #pragma unroll
            for (int jn = 0; jn < 2; ++jn) {
                O[im][jn][0] += sv.x * P[im][jn][0];
                O[im][jn][1] += sv.y * P[im][jn][1];
                O[im][jn][2] += sv.z * P[im][jn][2];
                O[im][jn][3] += sv.w * P[im][jn][3];
            }
        }

        if (jj == 2) __syncthreads();        // group done: swap buffers
        if (++jj == 3) { jj = 0; ++g; }
    }

    // epilogue: C/D layout col(d)=lane&15, row(m)=quad*4+reg
    #pragma unroll
    for (int im = 0; im < 5; ++im) {
        #pragma unroll
        for (int jn = 0; jn < 2; ++jn) {
            const int dd = d0 + wv * 32 + jn * 16 + ln;
            #pragma unroll
            for (int r = 0; r < 4; ++r) {
                const int m = im * 16 + quad * 4 + r;
                out[((size_t)(rt * W_ + m)) * DIM_ + dd] = O[im][jn][r];
            }
        }
    }
}

// ---------------------------------------------------------------------------
// conv2_fb: r6-proven fp32 reg-staging fallback (workspace too small for xb).
// ---------------------------------------------------------------------------
__global__ __launch_bounds__(256, 3) void conv2_fb(const float* __restrict__ x,
                                                   const float* __restrict__ ssel,
                                                   const ushort* __restrict__ wbT,
                                                   float* __restrict__ out)
{
    __shared__ ushort xsA[2][80 * 136];
    __shared__ float  sl[9][80];

    const int tid  = threadIdx.x;
    const int lane = tid & 63;
    const int wv   = tid >> 6;
    const int ln   = lane & 15;
    const int quad = lane >> 4;
    const int rt   = blockIdx.x;
    const int b    = rt / H_;
    const int h    = rt % H_;
    const int d0   = blockIdx.y * 128;

    int qm[5], qc[5];
    #pragma unroll
    for (int r = 0; r < 5; ++r) { int q = tid + 256 * r; qm[r] = q >> 4; qc[r] = q & 15; }

    floatx4 O[5][2];
    #pragma unroll
    for (int i = 0; i < 5; ++i)
        #pragma unroll
        for (int jn = 0; jn < 2; ++jn)
            O[i][jn] = (floatx4){0.f, 0.f, 0.f, 0.f};

    float4 fa[5], fb[5];
    bool   ok[5];

    auto stage_load = [&](int nit) {
        const int i = nit / 6, rem = nit % 6, cc = (rem / 3) * 128, jj = rem % 3;
        const int rr = h + i - 1;
        const bool rowok = (rr >= 0) && (rr < H_);
        const int rsafe = rowok ? rr : h;
        #pragma unroll
        for (int r = 0; r < 5; ++r) {
            const int col = qm[r] + jj - 1;
            const bool v = rowok && (col >= 0) && (col < W_);
            ok[r] = v;
            const float* f = x + ((size_t)(b * H_ + rsafe) * W_ + (v ? col : 0)) * CH_ + cc + qc[r] * 8;
            fa[r] = *(const float4*)f;
            fb[r] = *(const float4*)(f + 4);
        }
    };
    auto stage_write = [&](int nit) {
        #pragma unroll
        for (int r = 0; r < 5; ++r) {
            uint4 v = ok[r] ? make_uint4(pk2(fa[r].x, fa[r].y), pk2(fa[r].z, fa[r].w),
                                         pk2(fb[r].x, fb[r].y), pk2(fb[r].z, fb[r].w))
                            : make_uint4(0u, 0u, 0u, 0u);
            *(uint4*)&xsA[nit & 1][qm[r] * 136 + qc[r] * 8] = v;
        }
    };

    short8 Breg[8];
    auto loadB = [&](int nit) {
        const int i = nit / 6, rem = nit % 6, cc = (rem / 3) * 128, jj = rem % 3;
        const int k = 3 * i + jj;
        #pragma unroll
        for (int kk = 0; kk < 4; ++kk)
            #pragma unroll
            for (int jn = 0; jn < 2; ++jn)
                Breg[kk * 2 + jn] = *(const short8*)(wbT
                    + ((size_t)k * 256 + d0 + wv * 32 + jn * 16 + ln) * 256
                    + cc + kk * 32 + quad * 8);
    };

    stage_load(0);
    if (tid < 80) {
        float rv[9]; int cnt = 0;
        #pragma unroll
        for (int k = 0; k < 9; ++k) { rv[k] = ssel[k * NPIX + rt * W_ + tid]; cnt += (rv[k] != 0.f) ? 1 : 0; }
        const float norm = (cnt > 0) ? 9.f / (float)cnt : 0.f;
        #pragma unroll
        for (int k = 0; k < 9; ++k) sl[k][tid] = rv[k] * norm;
    }
    stage_write(0);
    loadB(0);
    __syncthreads();

    #pragma unroll 2
    for (int it = 0; it < 18; ++it) {
        const int i = it / 6, rem = it % 6, jj = rem % 3;
        const int k = 3 * i + jj;
        const ushort* bp = xsA[it & 1];

        if (it < 17) stage_load(it + 1);

        floatx4 P[5][2];
        #pragma unroll
        for (int im = 0; im < 5; ++im)
            #pragma unroll
            for (int jn = 0; jn < 2; ++jn)
                P[im][jn] = (floatx4){0.f, 0.f, 0.f, 0.f};

        #pragma unroll
        for (int kk = 0; kk < 4; ++kk) {
            short8 a[5];
            #pragma unroll
            for (int im = 0; im < 5; ++im)
                a[im] = *(const short8*)&bp[(im * 16 + ln) * 136 + kk * 32 + quad * 8];
            #pragma unroll
            for (int im = 0; im < 5; ++im)
                #pragma unroll
                for (int jn = 0; jn < 2; ++jn)
                    P[im][jn] = __builtin_amdgcn_mfma_f32_16x16x32_bf16(
                        a[im], Breg[kk * 2 + jn], P[im][jn], 0, 0, 0);
        }

        if (it < 17) stage_write(it + 1);
        if (it < 17) loadB(it + 1);

        #pragma unroll
        for (int im = 0; im < 5; ++im) {
            const float4 sv = *(const float4*)&sl[k][im * 16 + quad * 4];
            #pragma unroll
            for (int jn = 0; jn < 2; ++jn) {
                O[im][jn][0] += sv.x * P[im][jn][0];
                O[im][jn][1] += sv.y * P[im][jn][1];
                O[im][jn][2] += sv.z * P[im][jn][2];
                O[im][jn][3] += sv.w * P[im][jn][3];
            }
        }
        __syncthreads();
    }

    #pragma unroll
    for (int im = 0; im < 5; ++im)
        #pragma unroll
        for (int jn = 0; jn < 2; ++jn) {
            const int dd = d0 + wv * 32 + jn * 16 + ln;
            #pragma unroll
            for (int r = 0; r < 4; ++r) {
                const int m = im * 16 + quad * 4 + r;
                out[((size_t)(rt * W_ + m)) * DIM_ + dd] = O[im][jn][r];
            }
        }
}

extern "C" void kernel_launch(void* const* d_in, const int* in_sizes, int n_in,
                              void* d_out, int out_size, void* d_ws, size_t ws_size,
                              hipStream_t stream)
{
    const float* x   = (const float*)d_in[0];   // (4,80,80,256) f32
    const float* seg = (const float*)d_in[1];   // (4,80,80,22)  f32
    const float* cw  = (const float*)d_in[2];   // (256,3,3,256) f32
    float* out = (float*)d_out;

    float*  ssel = (float*)d_ws;                                   // 921600 B (raw)
    ushort* wbT  = (ushort*)((char*)d_ws + 921600);                // 1179648 B
    ushort* xb   = (ushort*)((char*)d_ws + 921600 + 1179648);      // 13107200 B
    const size_t need = 921600u + 1179648u + 13107200u;

    if (ws_size >= need) {
        prep<<<dim3(972 + 3200), dim3(256), 0, stream>>>(seg, cw, x, ssel, wbT, xb);
        conv2<<<dim3(B_ * H_, 2), dim3(256), 0, stream>>>(xb, ssel, wbT, out);
    } else {
        prep<<<dim3(972), dim3(256), 0, stream>>>(seg, cw, x, ssel, wbT, nullptr);
        conv2_fb<<<dim3(B_ * H_, 2), dim3(256), 0, stream>>>(x, ssel, wbT, out);
    }
}